// Round 7
// baseline (606.108 us; speedup 1.0000x reference)
//
#include <hip/hip_runtime.h>
#include <math.h>

#define GCOUNT 512
#define HDIM 128
#define EPG 2048                 // edge slots per graph (fixed across layers)
#define E_TOTAL (GCOUNT * EPG)   // 1,048,576
#define DEADE 0xFFFFFFFFu

typedef __attribute__((ext_vector_type(8))) short short8;
typedef __attribute__((ext_vector_type(4))) float f32x4;

__device__ inline unsigned short f2bf(float f) {
  unsigned int u = __float_as_uint(f);
  return (unsigned short)((u + 0x7FFFu + ((u >> 16) & 1u)) >> 16);
}
__device__ inline float bf2f(unsigned short s) {
  return __uint_as_float(((unsigned int)s) << 16);
}

// ---------------------------------------------------------------- W prepack: bf16 3-split, MFMA-B-fragment layout
// out: ushort Ws[s][kc][ct][lane][j]  (3 x 4 x 8 x 64 x 8 = 96 KB per W)
__global__ __launch_bounds__(256) void k_wsplit(const float* __restrict__ W,
                                                unsigned short* __restrict__ out) {
  int t = blockIdx.x * 256 + threadIdx.x;   // 2048 = (kc*8+ct)*64+lane
  int lane = t & 63;
  int ct = (t >> 6) & 7;
  int kc = t >> 9;
  int kbase = kc * 32 + (lane >> 4) * 8;
  int col = ct * 16 + (lane & 15);
#pragma unroll
  for (int j = 0; j < 8; j++) {
    float w = W[(size_t)(kbase + j) * HDIM + col];
    unsigned short h0 = f2bf(w);  float g0 = bf2f(h0);
    float r1 = w - g0;
    unsigned short h1 = f2bf(r1); float g1 = bf2f(h1);
    unsigned short h2 = f2bf(r1 - g1);
    int base = (kc * 8 + ct) * 512 + lane * 8 + j;
    out[base]         = h0;
    out[base + 16384] = h1;
    out[base + 32768] = h2;
  }
}

// ---------------------------------------------------------------- whole network, one block per graph
__global__ __launch_bounds__(1024, 4) void k_net(
    const float* __restrict__ xIn, const int* __restrict__ ei0,
    const unsigned short* __restrict__ Ws0,
    const unsigned short* __restrict__ Ws1,
    const unsigned short* __restrict__ Ws2,
    const float* __restrict__ b0, const float* __restrict__ p0,
    const float* __restrict__ b1, const float* __restrict__ p1,
    const float* __restrict__ b2, const float* __restrict__ p2,
    const float* __restrict__ Wg, const float* __restrict__ bgp,
    float* __restrict__ outp) {

  __shared__ __align__(16) float h_s[256 * 132];   // 135168 B
  __shared__ unsigned int es[EPG];                 // 8 KB  (src | dst<<16), DEADE = dead
  __shared__ unsigned short ss[EPG];               // 4 KB  CSR-sorted local src ids
  __shared__ int cnt[256];                         // degree -> nmap
  __shared__ int ofs[256];
  __shared__ int rp[260];
  __shared__ float dinv_s[256];
  __shared__ float rawsc_s[256];
  __shared__ float hd[256];                        // h' . Wg per row
  __shared__ float sc[256];                        // sort exchange -> att weights
  __shared__ int   idx[256];
  __shared__ float tn[256];
  __shared__ float accout[128];
  __shared__ float part[512];
  __shared__ float red[8];
  __shared__ float snorm_s;

  int g = blockIdx.x, t = threadIdx.x;
  int lane = t & 63, wv = t >> 6;
  int eb = g * EPG;
  float bgv = bgp[0];

  // ========== P0: stage x + edge loads to regs (waves 8-15) + zero cnt/accout
  {
    const float4* xg = (const float4*)(xIn + (size_t)g * 256 * HDIM);
    for (int i = t; i < 8192; i += 1024) {
      int r = i >> 5, q = i & 31;
      *(float4*)&h_s[r * 132 + (q << 2)] = xg[i];
    }
  }
  int esl[4], edl[4];
  if (wv >= 8) {
    int tt = t - 512;
#pragma unroll
    for (int q = 0; q < 4; q++) {
      int e = tt + q * 512;
      esl[q] = ei0[eb + e] - g * 256;
      edl[q] = ei0[E_TOTAL + eb + e] - g * 256;
    }
  }
  if (t < 256) cnt[t] = 0;
  if (t < 128) accout[t] = 0.f;
  __syncthreads();

  int n = 256;
#pragma unroll 1
  for (int layer = 0; layer < 3; layer++) {
    const unsigned short* Ws = (layer == 0) ? Ws0 : (layer == 1 ? Ws1 : Ws2);
    const float* bias = (layer == 0) ? b0 : (layer == 1 ? b1 : b2);
    const float* p    = (layer == 0) ? p0 : (layer == 1 ? p1 : p2);
    int k = (layer == 0) ? 205 : (layer == 1 ? 164 : 132);
    int T2 = (n + 31) >> 5;

    // ========== P1: GEMM (waves < T2) || histogram (+es write, L0) (waves >= 8)
    if (wv < T2) {
      int rbase = wv * 32;
      int arow = lane & 15, kgrp = (lane >> 4) * 8;
      f32x4 acc[2][8];
#pragma unroll
      for (int rt = 0; rt < 2; rt++)
#pragma unroll
        for (int ct = 0; ct < 8; ct++) acc[rt][ct] = (f32x4){0.f, 0.f, 0.f, 0.f};
#pragma unroll
      for (int kc = 0; kc < 4; kc++) {
        short8 fa0[2], fa1[2], fa2[2];
#pragma unroll
        for (int rt = 0; rt < 2; rt++) {
          const float* ap = &h_s[(rbase + rt * 16 + arow) * 132 + kc * 32 + kgrp];
          float4 x0 = *(const float4*)ap;
          float4 x1 = *(const float4*)(ap + 4);
          float v[8] = {x0.x, x0.y, x0.z, x0.w, x1.x, x1.y, x1.z, x1.w};
#pragma unroll
          for (int j = 0; j < 8; j++) {
            float a = v[j];
            unsigned short q0 = f2bf(a);  float g0 = bf2f(q0);
            float r1 = a - g0;
            unsigned short q1 = f2bf(r1); float g1 = bf2f(q1);
            unsigned short q2 = f2bf(r1 - g1);
            fa0[rt][j] = (short)q0; fa1[rt][j] = (short)q1; fa2[rt][j] = (short)q2;
          }
        }
#pragma unroll
        for (int ct = 0; ct < 8; ct++) {
          const unsigned short* wb = Ws + (kc * 8 + ct) * 512 + lane * 8;
          short8 w0 = *(const short8*)wb;
          short8 w1 = *(const short8*)(wb + 16384);
          short8 w2 = *(const short8*)(wb + 32768);
#pragma unroll
          for (int rt = 0; rt < 2; rt++) {
            acc[rt][ct] = __builtin_amdgcn_mfma_f32_16x16x32_bf16(fa0[rt], w0, acc[rt][ct], 0, 0, 0);
            acc[rt][ct] = __builtin_amdgcn_mfma_f32_16x16x32_bf16(fa0[rt], w1, acc[rt][ct], 0, 0, 0);
            acc[rt][ct] = __builtin_amdgcn_mfma_f32_16x16x32_bf16(fa1[rt], w0, acc[rt][ct], 0, 0, 0);
            acc[rt][ct] = __builtin_amdgcn_mfma_f32_16x16x32_bf16(fa1[rt], w1, acc[rt][ct], 0, 0, 0);
            acc[rt][ct] = __builtin_amdgcn_mfma_f32_16x16x32_bf16(fa0[rt], w2, acc[rt][ct], 0, 0, 0);
            acc[rt][ct] = __builtin_amdgcn_mfma_f32_16x16x32_bf16(fa2[rt], w0, acc[rt][ct], 0, 0, 0);
          }
        }
      }
      int crow = (lane >> 4) * 4, ccol = lane & 15;
#pragma unroll
      for (int rt = 0; rt < 2; rt++)
#pragma unroll
        for (int ct = 0; ct < 8; ct++)
#pragma unroll
          for (int reg = 0; reg < 4; reg++)
            h_s[(rbase + rt * 16 + crow + reg) * 132 + ct * 16 + ccol] = acc[rt][ct][reg];
    } else if (wv >= 8) {
      int tt = t - 512;
      if (layer == 0) {
#pragma unroll
        for (int q = 0; q < 4; q++) {
          atomicAdd(&cnt[edl[q]], 1);
          es[tt + q * 512] = (unsigned)esl[q] | ((unsigned)edl[q] << 16);
        }
      } else {
#pragma unroll
        for (int q = 0; q < 4; q++) {
          unsigned u = es[tt + q * 512];
          if (u != DEADE) atomicAdd(&cnt[u >> 16], 1);
        }
      }
    }
    __syncthreads();

    // ========== P2: dinv (t<256) + scan (wave0) + snorm (wave1)
    if (t < 256) dinv_s[t] = rsqrtf((float)cnt[t] + 1.0f);
    if (wv == 0) {
      int4 c4 = *(const int4*)&cnt[lane << 2];
      int s4 = c4.x + c4.y + c4.z + c4.w;
      int run = s4;
#pragma unroll
      for (int o = 1; o < 64; o <<= 1) {
        int v = __shfl_up(run, o);
        if (lane >= o) run += v;
      }
      int base = run - s4;
      int v1 = base + c4.x, v2 = v1 + c4.y, v3 = v2 + c4.z;
      int li = lane << 2;
      rp[li] = base; rp[li + 1] = v1; rp[li + 2] = v2; rp[li + 3] = v3;
      ofs[li] = base; ofs[li + 1] = v1; ofs[li + 2] = v2; ofs[li + 3] = v3;
      if (lane == 63) rp[256] = run;
    }
    if (wv == 1) {
      float q = p[lane] * p[lane] + p[lane + 64] * p[lane + 64];
#pragma unroll
      for (int o = 32; o > 0; o >>= 1) q += __shfl_xor(q, o);
      if (lane == 0) snorm_s = sqrtf(q);
    }
    __syncthreads();

    // ========== P3: scatter CSR (all threads) + preset nmap
    if (t < 256) cnt[t] = -1;
    for (int e = t; e < EPG; e += 1024) {
      unsigned u = es[e];
      if (u != DEADE) {
        int pos = atomicAdd(&ofs[u >> 16], 1);
        ss[pos] = (unsigned short)(u & 0xFFFFu);
      }
    }
    __syncthreads();

    // ========== P4: aggregate (dual-dst, batched masked loads) + score/gate dots
    int c = lane << 1;
    char* hb = (char*)h_s + ((size_t)lane << 3);
    float2 bV = *(const float2*)&bias[c];
    float2 pV = *(const float2*)&p[c];
    float2 wV = *(const float2*)&Wg[c];
    float a0[16], a1[16];
    int half = (n + 1) >> 1;
#pragma unroll 1
    for (int ii = 0; ii < 8; ii++) {
      int d0 = wv + (ii << 4);
      int d1 = d0 + half;
      bool h0v = (d0 < half);
      bool h1v = h0v && (d1 < n);
      int j0 = 0, e0 = 0, j1 = 0, e1 = 0;
      float dv0 = 0.f, dv1 = 0.f;
      if (h0v) { j0 = rp[d0]; e0 = rp[d0 + 1]; dv0 = dinv_s[d0]; }
      if (h1v) { j1 = rp[d1]; e1 = rp[d1 + 1]; dv1 = dinv_s[d1]; }
      float u00 = 0.f, u01 = 0.f, u10 = 0.f, u11 = 0.f;
      while (j0 < e0 || j1 < e1) {
        int s0i[8], s1i[8];
#pragma unroll
        for (int q = 0; q < 8; q++) {
          int aq = j0 + q; s0i[q] = ss[aq < e0 ? aq : 0];
          int bq = j1 + q; s1i[q] = ss[bq < e1 ? bq : 0];
        }
        float w0[8], w1[8]; float2 v0[8], v1[8];
#pragma unroll
        for (int q = 0; q < 8; q++) {
          w0[q] = (j0 + q < e0) ? dinv_s[s0i[q]] : 0.f;
          w1[q] = (j1 + q < e1) ? dinv_s[s1i[q]] : 0.f;
          v0[q] = *(const float2*)(hb + s0i[q] * 528);
          v1[q] = *(const float2*)(hb + s1i[q] * 528);
        }
#pragma unroll
        for (int q = 0; q < 8; q++) {
          u00 = fmaf(w0[q], v0[q].x, u00); u01 = fmaf(w0[q], v0[q].y, u01);
          u10 = fmaf(w1[q], v1[q].x, u10); u11 = fmaf(w1[q], v1[q].y, u11);
        }
        j0 += 8; j1 += 8;
        if (j0 > e0) j0 = e0;
        if (j1 > e1) j1 = e1;
      }
      if (h0v) {
        float2 vs = *(const float2*)(hb + d0 * 528);
        float r0 = fmaxf(fmaf(dv0, fmaf(vs.x, dv0, u00), bV.x), 0.f);
        float r1 = fmaxf(fmaf(dv0, fmaf(vs.y, dv0, u01), bV.y), 0.f);
        a0[ii] = r0; a1[ii] = r1;
        float s1 = fmaf(r0, pV.x, r1 * pV.y);
        float g1 = fmaf(r0, wV.x, r1 * wV.y);
#pragma unroll
        for (int o = 32; o > 0; o >>= 1) {
          s1 += __shfl_xor(s1, o);
          g1 += __shfl_xor(g1, o);
        }
        if (lane == 0) { rawsc_s[d0] = s1; hd[d0] = g1; }
      }
      if (h1v) {
        float2 vs = *(const float2*)(hb + d1 * 528);
        float r0 = fmaxf(fmaf(dv1, fmaf(vs.x, dv1, u10), bV.x), 0.f);
        float r1 = fmaxf(fmaf(dv1, fmaf(vs.y, dv1, u11), bV.y), 0.f);
        a0[ii + 8] = r0; a1[ii + 8] = r1;
        float s1 = fmaf(r0, pV.x, r1 * pV.y);
        float g1 = fmaf(r0, wV.x, r1 * wV.y);
#pragma unroll
        for (int o = 32; o > 0; o >>= 1) {
          s1 += __shfl_xor(s1, o);
          g1 += __shfl_xor(g1, o);
        }
        if (lane == 0) { rawsc_s[d1] = s1; hd[d1] = g1; }
      }
    }
    __syncthreads();

    // ========== P5: write aggregated h back
#pragma unroll
    for (int ii = 0; ii < 8; ii++) {
      int d0 = wv + (ii << 4);
      int d1 = d0 + half;
      if (d0 < half) *(float2*)(hb + d0 * 528) = make_float2(a0[ii], a1[ii]);
      if (d0 < half && d1 < n) *(float2*)(hb + d1 * 528) = make_float2(a0[ii + 8], a1[ii + 8]);
    }
    __syncthreads();

    // ========== P6: bitonic sort (keys = raw dot desc, idx asc)
    float key = -INFINITY;
    int id = t & 255;
    if (t < n) key = rawsc_s[t];
    for (int size = 2; size <= 256; size <<= 1) {
      for (int stride = size >> 1; stride > 0; stride >>= 1) {
        if (stride > 32) {
          if (t < 256) { sc[t] = key; idx[t] = id; }
          __syncthreads();
          float pk = 0.f; int pi = 0;
          if (t < 256) { pk = sc[t ^ stride]; pi = idx[t ^ stride]; }
          __syncthreads();
          if (t < 256) {
            bool want = ((t & size) == 0);
            bool lowr = ((t & stride) == 0);
            bool mineFirst = (key > pk) || (key == pk && id < pi);
            if (mineFirst != (want == lowr)) { key = pk; id = pi; }
          }
        } else {
          if (t < 256) {
            float pk = __shfl_xor(key, stride);
            int pi = __shfl_xor(id, stride);
            bool want = ((t & size) == 0);
            bool lowr = ((t & stride) == 0);
            bool mineFirst = (key > pk) || (key == pk && id < pi);
            if (mineFirst != (want == lowr)) { key = pk; id = pi; }
          }
        }
      }
    }
    if (t < 256) idx[t] = id;
    __syncthreads();

    // ========== P7: tn, nmap, gates + per-wave max
    float gate = -INFINITY;
    if (t < k) {
      float tnv = tanhf(key / snorm_s);
      tn[t] = tnv;
      cnt[id] = t;
      gate = fmaf(hd[id], tnv, bgv);
    }
    if (wv < 4) {
      float m = gate;
#pragma unroll
      for (int o = 32; o > 0; o >>= 1) m = fmaxf(m, __shfl_xor(m, o));
      if (lane == 0) red[wv] = m;
    }
    __syncthreads();

    // ========== P8: softmax exp+sum (waves 0-3) || edge remap in LDS (waves 8-15)
    float ex = 0.f;
    if (wv < 4) {
      float m = fmaxf(fmaxf(red[0], red[1]), fmaxf(red[2], red[3]));
      ex = (t < k) ? __expf(gate - m) : 0.f;
      float s = ex;
#pragma unroll
      for (int o = 32; o > 0; o >>= 1) s += __shfl_xor(s, o);
      if (lane == 0) red[4 + wv] = s;
    } else if (wv >= 8 && layer < 2) {
      int tt = t - 512;
#pragma unroll
      for (int q = 0; q < 4; q++) {
        int e = tt + q * 512;
        unsigned u = es[e];
        unsigned o = DEADE;
        if (u != DEADE) {
          int ns = cnt[u & 0xFFFFu], nd = cnt[u >> 16];
          if (ns >= 0 && nd >= 0) o = (unsigned)ns | ((unsigned)nd << 16);
        }
        es[e] = o;
      }
    }
    __syncthreads();

    // ========== P9: att weights + zero cnt for next layer
    if (t < 256) {
      float inv = 1.f / (red[4] + red[5] + red[6] + red[7]);
      float a = (t < k) ? ex * inv : 0.f;
      sc[t] = (layer == 2) ? a * tn[t] : a;
      cnt[t] = 0;
    }
    __syncthreads();

    if (layer < 2) {
      // ========== P10: in-LDS compaction (pooled = h[idx[r]] * tn[r])
      float cv[26];
      int m = 0;
      for (int v = t; v < k * 128; v += 1024) {
        int r = v >> 7;
        cv[m++] = h_s[idx[r] * 132 + (v & 127)] * tn[r];
      }
      __syncthreads();
      m = 0;
      for (int v = t; v < k * 128; v += 1024)
        h_s[(v >> 7) * 132 + (v & 127)] = cv[m++];
      __syncthreads();
      // ========== P11: attention partial sums over compacted rows
      if (t < 512) {
        int grp = t >> 7, c2 = t & 127;
        float pp = 0.f;
        for (int r = grp; r < k; r += 4) pp = fmaf(sc[r], h_s[r * 132 + c2], pp);
        part[t] = pp;
      }
      __syncthreads();
      if (t < 128) accout[t] += part[t] + part[128 + t] + part[256 + t] + part[384 + t];
      __syncthreads();
    } else {
      // ========== final attention (via idx, tn folded into sc) + output write
      if (t < 512) {
        int grp = t >> 7, c2 = t & 127;
        float pp = 0.f;
        for (int r = grp; r < k; r += 4) pp = fmaf(sc[r], h_s[idx[r] * 132 + c2], pp);
        part[t] = pp;
      }
      __syncthreads();
      if (t < 128)
        outp[(size_t)g * HDIM + t] =
            accout[t] + part[t] + part[128 + t] + part[256 + t] + part[384 + t];
    }
    n = k;
  }
}

// ================================================================ launch
extern "C" void kernel_launch(void* const* d_in, const int* in_sizes, int n_in,
                              void* d_out, int out_size, void* d_ws, size_t ws_size,
                              hipStream_t stream) {
  const float* x  = (const float*)d_in[0];
  const int*   ei = (const int*)d_in[1];
  const float* W0 = (const float*)d_in[2];
  const float* b0 = (const float*)d_in[3];
  const float* p0 = (const float*)d_in[4];
  const float* W1 = (const float*)d_in[5];
  const float* b1 = (const float*)d_in[6];
  const float* p1 = (const float*)d_in[7];
  const float* W2 = (const float*)d_in[8];
  const float* b2 = (const float*)d_in[9];
  const float* p2 = (const float*)d_in[10];
  const float* Wg = (const float*)d_in[11];
  const float* bg = (const float*)d_in[12];
  float* out = (float*)d_out;

  unsigned char* ws = (unsigned char*)d_ws;
  unsigned short* Wsp0 = (unsigned short*)(ws);
  unsigned short* Wsp1 = (unsigned short*)(ws + 98304ull);
  unsigned short* Wsp2 = (unsigned short*)(ws + 196608ull);

  k_wsplit<<<8, 256, 0, stream>>>(W0, Wsp0);
  k_wsplit<<<8, 256, 0, stream>>>(W1, Wsp1);
  k_wsplit<<<8, 256, 0, stream>>>(W2, Wsp2);
  k_net<<<GCOUNT, 1024, 0, stream>>>(x, ei, Wsp0, Wsp1, Wsp2,
                                     b0, p0, b1, p1, b2, p2, Wg, bg, out);
}

// Round 8
// 423.676 us; speedup vs baseline: 1.4306x; 1.4306x over previous
//
#include <hip/hip_runtime.h>
#include <math.h>

#define GCOUNT 512
#define HDIM 128
#define EPG 2048                 // edge slots per graph (fixed across layers)
#define E_TOTAL (GCOUNT * EPG)   // 1,048,576
#define DEADE 0xFFFFFFFFu

typedef __attribute__((ext_vector_type(8))) short short8;
typedef __attribute__((ext_vector_type(4))) float f32x4;

__device__ inline unsigned short f2bf(float f) {
  unsigned int u = __float_as_uint(f);
  return (unsigned short)((u + 0x7FFFu + ((u >> 16) & 1u)) >> 16);
}
__device__ inline float bf2f(unsigned short s) {
  return __uint_as_float(((unsigned int)s) << 16);
}

// ---------------------------------------------------------------- W prepack: bf16 3-split, MFMA-B-fragment layout
__global__ __launch_bounds__(256) void k_wsplit(const float* __restrict__ W,
                                                unsigned short* __restrict__ out) {
  int t = blockIdx.x * 256 + threadIdx.x;   // 2048 = (kc*8+ct)*64+lane
  int lane = t & 63;
  int ct = (t >> 6) & 7;
  int kc = t >> 9;
  int kbase = kc * 32 + (lane >> 4) * 8;
  int col = ct * 16 + (lane & 15);
#pragma unroll
  for (int j = 0; j < 8; j++) {
    float w = W[(size_t)(kbase + j) * HDIM + col];
    unsigned short h0 = f2bf(w);  float g0 = bf2f(h0);
    float r1 = w - g0;
    unsigned short h1 = f2bf(r1); float g1 = bf2f(h1);
    unsigned short h2 = f2bf(r1 - g1);
    int base = (kc * 8 + ct) * 512 + lane * 8 + j;
    out[base]         = h0;
    out[base + 16384] = h1;
    out[base + 32768] = h2;
  }
}

// ---------------------------------------------------------------- whole network, one block per graph
__global__ __launch_bounds__(1024, 4) void k_net(
    const float* __restrict__ xIn, const int* __restrict__ ei0,
    const unsigned short* __restrict__ Ws0,
    const unsigned short* __restrict__ Ws1,
    const unsigned short* __restrict__ Ws2,
    const float* __restrict__ b0, const float* __restrict__ p0,
    const float* __restrict__ b1, const float* __restrict__ p1,
    const float* __restrict__ b2, const float* __restrict__ p2,
    const float* __restrict__ Wg, const float* __restrict__ bgp,
    float* __restrict__ outp) {

  __shared__ __align__(16) float h_s[256 * 132];   // 135168 B
  __shared__ unsigned int es[EPG];                 // 8 KB  (src | dst<<16), DEADE = dead
  __shared__ unsigned short ss[EPG];               // 4 KB  CSR-sorted local src ids
  __shared__ int cnt[256];                         // degree -> nmap
  __shared__ int ofs[256];
  __shared__ int rp[260];
  __shared__ float dinv_s[256];
  __shared__ float rawsc_s[256];
  __shared__ float hd[256];                        // h' . Wg per row
  __shared__ float sc[256];                        // sort exchange -> att weights
  __shared__ int   idx[256];
  __shared__ float tn[256];
  __shared__ float accout[128];
  __shared__ float part[512];
  __shared__ float red[8];
  __shared__ float snorm_s;

  int g = blockIdx.x, t = threadIdx.x;
  int lane = t & 63, wv = t >> 6;
  int eb = g * EPG;
  float bgv = bgp[0];

  // ========== P0: stage x + edge loads to regs (waves 8-15) + zero cnt/accout
  {
    const float4* xg = (const float4*)(xIn + (size_t)g * 256 * HDIM);
    for (int i = t; i < 8192; i += 1024) {
      int r = i >> 5, q = i & 31;
      *(float4*)&h_s[r * 132 + (q << 2)] = xg[i];
    }
  }
  int esl[4], edl[4];
  if (wv >= 8) {
    int tt = t - 512;
#pragma unroll
    for (int q = 0; q < 4; q++) {
      int e = tt + q * 512;
      esl[q] = ei0[eb + e] - g * 256;
      edl[q] = ei0[E_TOTAL + eb + e] - g * 256;
    }
  }
  if (t < 256) cnt[t] = 0;
  if (t < 128) accout[t] = 0.f;
  __syncthreads();

  int n = 256;
#pragma unroll 1
  for (int layer = 0; layer < 3; layer++) {
    const unsigned short* Ws = (layer == 0) ? Ws0 : (layer == 1 ? Ws1 : Ws2);
    const float* bias = (layer == 0) ? b0 : (layer == 1 ? b1 : b2);
    const float* p    = (layer == 0) ? p0 : (layer == 1 ? p1 : p2);
    int k = (layer == 0) ? 205 : (layer == 1 ? 164 : 132);
    int T2 = (n + 31) >> 5;

    // ========== P1: GEMM (waves < T2) || histogram (+es write, L0) (waves >= 8)
    if (wv < T2) {
      int rbase = wv * 32;
      int arow = lane & 15, kgrp = (lane >> 4) * 8;
      f32x4 acc[2][8];
#pragma unroll
      for (int rt = 0; rt < 2; rt++)
#pragma unroll
        for (int ct = 0; ct < 8; ct++) acc[rt][ct] = (f32x4){0.f, 0.f, 0.f, 0.f};
#pragma unroll
      for (int kc = 0; kc < 4; kc++) {
        short8 fa0[2], fa1[2], fa2[2];
#pragma unroll
        for (int rt = 0; rt < 2; rt++) {
          const float* ap = &h_s[(rbase + rt * 16 + arow) * 132 + kc * 32 + kgrp];
          float4 x0 = *(const float4*)ap;
          float4 x1 = *(const float4*)(ap + 4);
          float v[8] = {x0.x, x0.y, x0.z, x0.w, x1.x, x1.y, x1.z, x1.w};
#pragma unroll
          for (int j = 0; j < 8; j++) {
            float a = v[j];
            unsigned short q0 = f2bf(a);  float g0 = bf2f(q0);
            float r1 = a - g0;
            unsigned short q1 = f2bf(r1); float g1 = bf2f(q1);
            unsigned short q2 = f2bf(r1 - g1);
            fa0[rt][j] = (short)q0; fa1[rt][j] = (short)q1; fa2[rt][j] = (short)q2;
          }
        }
#pragma unroll
        for (int ct = 0; ct < 8; ct++) {
          const unsigned short* wb = Ws + (kc * 8 + ct) * 512 + lane * 8;
          short8 w0 = *(const short8*)wb;
          short8 w1 = *(const short8*)(wb + 16384);
          short8 w2 = *(const short8*)(wb + 32768);
#pragma unroll
          for (int rt = 0; rt < 2; rt++) {
            acc[rt][ct] = __builtin_amdgcn_mfma_f32_16x16x32_bf16(fa0[rt], w0, acc[rt][ct], 0, 0, 0);
            acc[rt][ct] = __builtin_amdgcn_mfma_f32_16x16x32_bf16(fa0[rt], w1, acc[rt][ct], 0, 0, 0);
            acc[rt][ct] = __builtin_amdgcn_mfma_f32_16x16x32_bf16(fa1[rt], w0, acc[rt][ct], 0, 0, 0);
            acc[rt][ct] = __builtin_amdgcn_mfma_f32_16x16x32_bf16(fa1[rt], w1, acc[rt][ct], 0, 0, 0);
            acc[rt][ct] = __builtin_amdgcn_mfma_f32_16x16x32_bf16(fa0[rt], w2, acc[rt][ct], 0, 0, 0);
            acc[rt][ct] = __builtin_amdgcn_mfma_f32_16x16x32_bf16(fa2[rt], w0, acc[rt][ct], 0, 0, 0);
          }
        }
      }
      int crow = (lane >> 4) * 4, ccol = lane & 15;
#pragma unroll
      for (int rt = 0; rt < 2; rt++)
#pragma unroll
        for (int ct = 0; ct < 8; ct++)
#pragma unroll
          for (int reg = 0; reg < 4; reg++)
            h_s[(rbase + rt * 16 + crow + reg) * 132 + ct * 16 + ccol] = acc[rt][ct][reg];
    } else if (wv >= 8) {
      int tt = t - 512;
      if (layer == 0) {
#pragma unroll
        for (int q = 0; q < 4; q++) {
          atomicAdd(&cnt[edl[q]], 1);
          es[tt + q * 512] = (unsigned)esl[q] | ((unsigned)edl[q] << 16);
        }
      } else {
#pragma unroll
        for (int q = 0; q < 4; q++) {
          unsigned u = es[tt + q * 512];
          if (u != DEADE) atomicAdd(&cnt[u >> 16], 1);
        }
      }
    }
    __syncthreads();

    // ========== P2: dinv (t<256) + scan (wave0) + snorm (wave1)
    if (t < 256) dinv_s[t] = rsqrtf((float)cnt[t] + 1.0f);
    if (wv == 0) {
      int4 c4 = *(const int4*)&cnt[lane << 2];
      int s4 = c4.x + c4.y + c4.z + c4.w;
      int run = s4;
#pragma unroll
      for (int o = 1; o < 64; o <<= 1) {
        int v = __shfl_up(run, o);
        if (lane >= o) run += v;
      }
      int base = run - s4;
      int v1 = base + c4.x, v2 = v1 + c4.y, v3 = v2 + c4.z;
      int li = lane << 2;
      rp[li] = base; rp[li + 1] = v1; rp[li + 2] = v2; rp[li + 3] = v3;
      ofs[li] = base; ofs[li + 1] = v1; ofs[li + 2] = v2; ofs[li + 3] = v3;
      if (lane == 63) rp[256] = run;
    }
    if (wv == 1) {
      float q = p[lane] * p[lane] + p[lane + 64] * p[lane + 64];
#pragma unroll
      for (int o = 32; o > 0; o >>= 1) q += __shfl_xor(q, o);
      if (lane == 0) snorm_s = sqrtf(q);
    }
    __syncthreads();

    // ========== P3: scatter CSR (all threads) + preset nmap
    if (t < 256) cnt[t] = -1;
    for (int e = t; e < EPG; e += 1024) {
      unsigned u = es[e];
      if (u != DEADE) {
        int pos = atomicAdd(&ofs[u >> 16], 1);
        ss[pos] = (unsigned short)(u & 0xFFFFu);
      }
    }
    __syncthreads();

    // ========== P4: aggregate (dual-dst, batched masked loads) + score/gate dots
    int c = lane << 1;
    char* hb = (char*)h_s + ((size_t)lane << 3);
    float2 bV = *(const float2*)&bias[c];
    float2 pV = *(const float2*)&p[c];
    float2 wV = *(const float2*)&Wg[c];
    float a0[16], a1[16];
    int half = (n + 1) >> 1;
#pragma unroll
    for (int ii = 0; ii < 8; ii++) {
      int d0 = wv + (ii << 4);
      int d1 = d0 + half;
      bool h0v = (d0 < half);
      bool h1v = h0v && (d1 < n);
      int j0 = 0, e0 = 0, j1 = 0, e1 = 0;
      float dv0 = 0.f, dv1 = 0.f;
      if (h0v) { j0 = rp[d0]; e0 = rp[d0 + 1]; dv0 = dinv_s[d0]; }
      if (h1v) { j1 = rp[d1]; e1 = rp[d1 + 1]; dv1 = dinv_s[d1]; }
      float u00 = 0.f, u01 = 0.f, u10 = 0.f, u11 = 0.f;
      while (j0 < e0 || j1 < e1) {
        int s0i[8], s1i[8];
#pragma unroll
        for (int q = 0; q < 8; q++) {
          int aq = j0 + q; s0i[q] = ss[aq < e0 ? aq : 0];
          int bq = j1 + q; s1i[q] = ss[bq < e1 ? bq : 0];
        }
        float w0[8], w1[8]; float2 v0[8], v1[8];
#pragma unroll
        for (int q = 0; q < 8; q++) {
          w0[q] = (j0 + q < e0) ? dinv_s[s0i[q]] : 0.f;
          w1[q] = (j1 + q < e1) ? dinv_s[s1i[q]] : 0.f;
          v0[q] = *(const float2*)(hb + s0i[q] * 528);
          v1[q] = *(const float2*)(hb + s1i[q] * 528);
        }
#pragma unroll
        for (int q = 0; q < 8; q++) {
          u00 = fmaf(w0[q], v0[q].x, u00); u01 = fmaf(w0[q], v0[q].y, u01);
          u10 = fmaf(w1[q], v1[q].x, u10); u11 = fmaf(w1[q], v1[q].y, u11);
        }
        j0 += 8; j1 += 8;
        if (j0 > e0) j0 = e0;
        if (j1 > e1) j1 = e1;
      }
      if (h0v) {
        float2 vs = *(const float2*)(hb + d0 * 528);
        float r0 = fmaxf(fmaf(dv0, fmaf(vs.x, dv0, u00), bV.x), 0.f);
        float r1 = fmaxf(fmaf(dv0, fmaf(vs.y, dv0, u01), bV.y), 0.f);
        a0[ii] = r0; a1[ii] = r1;
        float s1 = fmaf(r0, pV.x, r1 * pV.y);
        float g1 = fmaf(r0, wV.x, r1 * wV.y);
#pragma unroll
        for (int o = 32; o > 0; o >>= 1) {
          s1 += __shfl_xor(s1, o);
          g1 += __shfl_xor(g1, o);
        }
        if (lane == 0) { rawsc_s[d0] = s1; hd[d0] = g1; }
      } else { a0[ii] = 0.f; a1[ii] = 0.f; }
      if (h1v) {
        float2 vs = *(const float2*)(hb + d1 * 528);
        float r0 = fmaxf(fmaf(dv1, fmaf(vs.x, dv1, u10), bV.x), 0.f);
        float r1 = fmaxf(fmaf(dv1, fmaf(vs.y, dv1, u11), bV.y), 0.f);
        a0[ii + 8] = r0; a1[ii + 8] = r1;
        float s1 = fmaf(r0, pV.x, r1 * pV.y);
        float g1 = fmaf(r0, wV.x, r1 * wV.y);
#pragma unroll
        for (int o = 32; o > 0; o >>= 1) {
          s1 += __shfl_xor(s1, o);
          g1 += __shfl_xor(g1, o);
        }
        if (lane == 0) { rawsc_s[d1] = s1; hd[d1] = g1; }
      } else { a0[ii + 8] = 0.f; a1[ii + 8] = 0.f; }
    }
    __syncthreads();

    // ========== P5: write aggregated h back
#pragma unroll
    for (int ii = 0; ii < 8; ii++) {
      int d0 = wv + (ii << 4);
      int d1 = d0 + half;
      if (d0 < half) *(float2*)(hb + d0 * 528) = make_float2(a0[ii], a1[ii]);
      if (d0 < half && d1 < n) *(float2*)(hb + d1 * 528) = make_float2(a0[ii + 8], a1[ii + 8]);
    }
    __syncthreads();

    // ========== P6: bitonic sort (keys = raw dot desc, idx asc)
    float key = -INFINITY;
    int id = t & 255;
    if (t < n) key = rawsc_s[t];
    for (int size = 2; size <= 256; size <<= 1) {
      for (int stride = size >> 1; stride > 0; stride >>= 1) {
        if (stride > 32) {
          if (t < 256) { sc[t] = key; idx[t] = id; }
          __syncthreads();
          float pk = 0.f; int pi = 0;
          if (t < 256) { pk = sc[t ^ stride]; pi = idx[t ^ stride]; }
          __syncthreads();
          if (t < 256) {
            bool want = ((t & size) == 0);
            bool lowr = ((t & stride) == 0);
            bool mineFirst = (key > pk) || (key == pk && id < pi);
            if (mineFirst != (want == lowr)) { key = pk; id = pi; }
          }
        } else {
          if (t < 256) {
            float pk = __shfl_xor(key, stride);
            int pi = __shfl_xor(id, stride);
            bool want = ((t & size) == 0);
            bool lowr = ((t & stride) == 0);
            bool mineFirst = (key > pk) || (key == pk && id < pi);
            if (mineFirst != (want == lowr)) { key = pk; id = pi; }
          }
        }
      }
    }
    if (t < 256) idx[t] = id;
    __syncthreads();

    // ========== P7: tn, nmap, gates + per-wave max
    float gate = -INFINITY;
    if (t < k) {
      float tnv = tanhf(key / snorm_s);
      tn[t] = tnv;
      cnt[id] = t;
      gate = fmaf(hd[id], tnv, bgv);
    }
    if (wv < 4) {
      float m = gate;
#pragma unroll
      for (int o = 32; o > 0; o >>= 1) m = fmaxf(m, __shfl_xor(m, o));
      if (lane == 0) red[wv] = m;
    }
    __syncthreads();

    // ========== P8: softmax exp+sum (waves 0-3) || edge remap in LDS (waves 8-15)
    float ex = 0.f;
    if (wv < 4) {
      float m = fmaxf(fmaxf(red[0], red[1]), fmaxf(red[2], red[3]));
      ex = (t < k) ? __expf(gate - m) : 0.f;
      float s = ex;
#pragma unroll
      for (int o = 32; o > 0; o >>= 1) s += __shfl_xor(s, o);
      if (lane == 0) red[4 + wv] = s;
    } else if (wv >= 8 && layer < 2) {
      int tt = t - 512;
#pragma unroll
      for (int q = 0; q < 4; q++) {
        int e = tt + q * 512;
        unsigned u = es[e];
        unsigned o = DEADE;
        if (u != DEADE) {
          int ns = cnt[u & 0xFFFFu], nd = cnt[u >> 16];
          if (ns >= 0 && nd >= 0) o = (unsigned)ns | ((unsigned)nd << 16);
        }
        es[e] = o;
      }
    }
    __syncthreads();

    // ========== P9: att weights + zero cnt for next layer
    if (t < 256) {
      float inv = 1.f / (red[4] + red[5] + red[6] + red[7]);
      float a = (t < k) ? ex * inv : 0.f;
      sc[t] = (layer == 2) ? a * tn[t] : a;
      cnt[t] = 0;
    }
    __syncthreads();

    if (layer < 2) {
      // ========== P10: in-LDS compaction, static 26-step unroll (205*128 <= 26*1024)
      float cv[26];
      int kk128 = k * 128;
#pragma unroll
      for (int m = 0; m < 26; m++) {
        int v = t + (m << 10);
        int r = v >> 7;
        cv[m] = (v < kk128) ? h_s[idx[r] * 132 + (v & 127)] * tn[r] : 0.f;
      }
      __syncthreads();
#pragma unroll
      for (int m = 0; m < 26; m++) {
        int v = t + (m << 10);
        if (v < kk128) h_s[(v >> 7) * 132 + (v & 127)] = cv[m];
      }
      __syncthreads();
      // ========== P11: attention partial sums over compacted rows
      if (t < 512) {
        int grp = t >> 7, c2 = t & 127;
        float pp = 0.f;
        for (int r = grp; r < k; r += 4) pp = fmaf(sc[r], h_s[r * 132 + c2], pp);
        part[t] = pp;
      }
      __syncthreads();
      if (t < 128) accout[t] += part[t] + part[128 + t] + part[256 + t] + part[384 + t];
      __syncthreads();
    } else {
      // ========== final attention (via idx, tn folded into sc) + output write
      if (t < 512) {
        int grp = t >> 7, c2 = t & 127;
        float pp = 0.f;
        for (int r = grp; r < k; r += 4) pp = fmaf(sc[r], h_s[idx[r] * 132 + c2], pp);
        part[t] = pp;
      }
      __syncthreads();
      if (t < 128)
        outp[(size_t)g * HDIM + t] =
            accout[t] + part[t] + part[128 + t] + part[256 + t] + part[384 + t];
    }
    n = k;
  }
}

// ================================================================ launch
extern "C" void kernel_launch(void* const* d_in, const int* in_sizes, int n_in,
                              void* d_out, int out_size, void* d_ws, size_t ws_size,
                              hipStream_t stream) {
  const float* x  = (const float*)d_in[0];
  const int*   ei = (const int*)d_in[1];
  const float* W0 = (const float*)d_in[2];
  const float* b0 = (const float*)d_in[3];
  const float* p0 = (const float*)d_in[4];
  const float* W1 = (const float*)d_in[5];
  const float* b1 = (const float*)d_in[6];
  const float* p1 = (const float*)d_in[7];
  const float* W2 = (const float*)d_in[8];
  const float* b2 = (const float*)d_in[9];
  const float* p2 = (const float*)d_in[10];
  const float* Wg = (const float*)d_in[11];
  const float* bg = (const float*)d_in[12];
  float* out = (float*)d_out;

  unsigned char* ws = (unsigned char*)d_ws;
  unsigned short* Wsp0 = (unsigned short*)(ws);
  unsigned short* Wsp1 = (unsigned short*)(ws + 98304ull);
  unsigned short* Wsp2 = (unsigned short*)(ws + 196608ull);

  k_wsplit<<<8, 256, 0, stream>>>(W0, Wsp0);
  k_wsplit<<<8, 256, 0, stream>>>(W1, Wsp1);
  k_wsplit<<<8, 256, 0, stream>>>(W2, Wsp2);
  k_net<<<GCOUNT, 1024, 0, stream>>>(x, ei, Wsp0, Wsp1, Wsp2,
                                     b0, p0, b1, p1, b2, p2, Wg, bg, out);
}

// Round 9
// 417.332 us; speedup vs baseline: 1.4523x; 1.0152x over previous
//
#include <hip/hip_runtime.h>
#include <math.h>

#define GCOUNT 512
#define HDIM 128
#define EPG 2048                 // edge slots per graph (fixed across layers)
#define E_TOTAL (GCOUNT * EPG)   // 1,048,576
#define DEADE 0xFFFFFFFFu

typedef __attribute__((ext_vector_type(8))) short short8;
typedef __attribute__((ext_vector_type(4))) float f32x4;

__device__ inline unsigned short f2bf(float f) {
  unsigned int u = __float_as_uint(f);
  return (unsigned short)((u + 0x7FFFu + ((u >> 16) & 1u)) >> 16);
}
__device__ inline float bf2f(unsigned short s) {
  return __uint_as_float(((unsigned int)s) << 16);
}

// ---------------------------------------------------------------- W prepack: bf16 3-split, MFMA-B-fragment layout
__global__ __launch_bounds__(256) void k_wsplit(const float* __restrict__ W,
                                                unsigned short* __restrict__ out) {
  int t = blockIdx.x * 256 + threadIdx.x;   // 2048 = (kc*8+ct)*64+lane
  int lane = t & 63;
  int ct = (t >> 6) & 7;
  int kc = t >> 9;
  int kbase = kc * 32 + (lane >> 4) * 8;
  int col = ct * 16 + (lane & 15);
#pragma unroll
  for (int j = 0; j < 8; j++) {
    float w = W[(size_t)(kbase + j) * HDIM + col];
    unsigned short h0 = f2bf(w);  float g0 = bf2f(h0);
    float r1 = w - g0;
    unsigned short h1 = f2bf(r1); float g1 = bf2f(h1);
    unsigned short h2 = f2bf(r1 - g1);
    int base = (kc * 8 + ct) * 512 + lane * 8 + j;
    out[base]         = h0;
    out[base + 16384] = h1;
    out[base + 32768] = h2;
  }
}

// ---------------------------------------------------------------- whole network, one block per graph
__global__ __launch_bounds__(1024, 4) void k_net(
    const float* __restrict__ xIn, const int* __restrict__ ei0,
    const unsigned short* __restrict__ Ws0,
    const unsigned short* __restrict__ Ws1,
    const unsigned short* __restrict__ Ws2,
    const float* __restrict__ b0, const float* __restrict__ p0,
    const float* __restrict__ b1, const float* __restrict__ p1,
    const float* __restrict__ b2, const float* __restrict__ p2,
    const float* __restrict__ Wg, const float* __restrict__ bgp,
    float* __restrict__ outp) {

  __shared__ __align__(16) float h_s[256 * 132];   // 135168 B
  __shared__ unsigned int es[EPG];                 // 8 KB  (src | dst<<16), DEADE = dead
  __shared__ unsigned short ss[EPG];               // 4 KB  CSR-sorted local src ids
  __shared__ int cnt[256];                         // degree -> nmap
  __shared__ int ofs[256];
  __shared__ int rp[260];
  __shared__ float dinv_s[256];
  __shared__ float rawsc_s[256];
  __shared__ float hd[256];                        // h' . Wg per row
  __shared__ float sc[256];                        // sort exchange -> att weights
  __shared__ int   idx[256];
  __shared__ float tn[256];
  __shared__ float accout[128];
  __shared__ float part[512];
  __shared__ float red[8];
  __shared__ float snorm_s;

  int g = blockIdx.x, t = threadIdx.x;
  int lane = t & 63, wv = t >> 6;
  int eb = g * EPG;
  float bgv = bgp[0];

  // ========== P0: stage x + edge loads to regs (waves 8-15) + zero cnt/accout
  {
    const float4* xg = (const float4*)(xIn + (size_t)g * 256 * HDIM);
    for (int i = t; i < 8192; i += 1024) {
      int r = i >> 5, q = i & 31;
      *(float4*)&h_s[r * 132 + (q << 2)] = xg[i];
    }
  }
  int esl[4], edl[4];
  if (wv >= 8) {
    int tt = t - 512;
#pragma unroll
    for (int q = 0; q < 4; q++) {
      int e = tt + q * 512;
      esl[q] = ei0[eb + e] - g * 256;
      edl[q] = ei0[E_TOTAL + eb + e] - g * 256;
    }
  }
  if (t < 256) cnt[t] = 0;
  if (t < 128) accout[t] = 0.f;
  __syncthreads();

  int n = 256;
#pragma unroll 1
  for (int layer = 0; layer < 3; layer++) {
    const unsigned short* Ws = (layer == 0) ? Ws0 : (layer == 1 ? Ws1 : Ws2);
    const float* bias = (layer == 0) ? b0 : (layer == 1 ? b1 : b2);
    const float* p    = (layer == 0) ? p0 : (layer == 1 ? p1 : p2);
    int k = (layer == 0) ? 205 : (layer == 1 ? 164 : 132);
    int T2 = (n + 31) >> 5;

    // ========== P1: GEMM (waves < T2) || histogram (+es write, L0) (waves >= 8)
    if (wv < T2) {
      int rbase = wv * 32;
      int arow = lane & 15, kgrp = (lane >> 4) * 8;
      f32x4 acc[2][8];
#pragma unroll
      for (int rt = 0; rt < 2; rt++)
#pragma unroll
        for (int ct = 0; ct < 8; ct++) acc[rt][ct] = (f32x4){0.f, 0.f, 0.f, 0.f};
#pragma unroll
      for (int kc = 0; kc < 4; kc++) {
        short8 fa0[2], fa1[2], fa2[2];
#pragma unroll
        for (int rt = 0; rt < 2; rt++) {
          const float* ap = &h_s[(rbase + rt * 16 + arow) * 132 + kc * 32 + kgrp];
          float4 x0 = *(const float4*)ap;
          float4 x1 = *(const float4*)(ap + 4);
          float v[8] = {x0.x, x0.y, x0.z, x0.w, x1.x, x1.y, x1.z, x1.w};
#pragma unroll
          for (int j = 0; j < 8; j++) {
            float a = v[j];
            unsigned short q0 = f2bf(a);  float g0 = bf2f(q0);
            float r1 = a - g0;
            unsigned short q1 = f2bf(r1); float g1 = bf2f(q1);
            unsigned short q2 = f2bf(r1 - g1);
            fa0[rt][j] = (short)q0; fa1[rt][j] = (short)q1; fa2[rt][j] = (short)q2;
          }
        }
#pragma unroll
        for (int ct = 0; ct < 8; ct++) {
          const unsigned short* wb = Ws + (kc * 8 + ct) * 512 + lane * 8;
          short8 w0 = *(const short8*)wb;
          short8 w1 = *(const short8*)(wb + 16384);
          short8 w2 = *(const short8*)(wb + 32768);
#pragma unroll
          for (int rt = 0; rt < 2; rt++) {
            acc[rt][ct] = __builtin_amdgcn_mfma_f32_16x16x32_bf16(fa0[rt], w0, acc[rt][ct], 0, 0, 0);
            acc[rt][ct] = __builtin_amdgcn_mfma_f32_16x16x32_bf16(fa0[rt], w1, acc[rt][ct], 0, 0, 0);
            acc[rt][ct] = __builtin_amdgcn_mfma_f32_16x16x32_bf16(fa1[rt], w0, acc[rt][ct], 0, 0, 0);
            acc[rt][ct] = __builtin_amdgcn_mfma_f32_16x16x32_bf16(fa1[rt], w1, acc[rt][ct], 0, 0, 0);
            acc[rt][ct] = __builtin_amdgcn_mfma_f32_16x16x32_bf16(fa0[rt], w2, acc[rt][ct], 0, 0, 0);
            acc[rt][ct] = __builtin_amdgcn_mfma_f32_16x16x32_bf16(fa2[rt], w0, acc[rt][ct], 0, 0, 0);
          }
        }
      }
      int crow = (lane >> 4) * 4, ccol = lane & 15;
#pragma unroll
      for (int rt = 0; rt < 2; rt++)
#pragma unroll
        for (int ct = 0; ct < 8; ct++)
#pragma unroll
          for (int reg = 0; reg < 4; reg++)
            h_s[(rbase + rt * 16 + crow + reg) * 132 + ct * 16 + ccol] = acc[rt][ct][reg];
    } else if (wv >= 8) {
      int tt = t - 512;
      if (layer == 0) {
#pragma unroll
        for (int q = 0; q < 4; q++) {
          atomicAdd(&cnt[edl[q]], 1);
          es[tt + q * 512] = (unsigned)esl[q] | ((unsigned)edl[q] << 16);
        }
      } else {
#pragma unroll
        for (int q = 0; q < 4; q++) {
          unsigned u = es[tt + q * 512];
          if (u != DEADE) atomicAdd(&cnt[u >> 16], 1);
        }
      }
    }
    __syncthreads();

    // ========== P2: dinv (t<256) + scan (wave0) + snorm (wave1)
    if (t < 256) dinv_s[t] = rsqrtf((float)cnt[t] + 1.0f);
    if (wv == 0) {
      int4 c4 = *(const int4*)&cnt[lane << 2];
      int s4 = c4.x + c4.y + c4.z + c4.w;
      int run = s4;
#pragma unroll
      for (int o = 1; o < 64; o <<= 1) {
        int v = __shfl_up(run, o);
        if (lane >= o) run += v;
      }
      int base = run - s4;
      int v1 = base + c4.x, v2 = v1 + c4.y, v3 = v2 + c4.z;
      int li = lane << 2;
      rp[li] = base; rp[li + 1] = v1; rp[li + 2] = v2; rp[li + 3] = v3;
      ofs[li] = base; ofs[li + 1] = v1; ofs[li + 2] = v2; ofs[li + 3] = v3;
      if (lane == 63) rp[256] = run;
    }
    if (wv == 1) {
      float q = p[lane] * p[lane] + p[lane + 64] * p[lane + 64];
#pragma unroll
      for (int o = 32; o > 0; o >>= 1) q += __shfl_xor(q, o);
      if (lane == 0) snorm_s = sqrtf(q);
    }
    __syncthreads();

    // ========== P3: scatter CSR (all threads) + preset nmap
    if (t < 256) cnt[t] = -1;
    for (int e = t; e < EPG; e += 1024) {
      unsigned u = es[e];
      if (u != DEADE) {
        int pos = atomicAdd(&ofs[u >> 16], 1);
        ss[pos] = (unsigned short)(u & 0xFFFFu);
      }
    }
    __syncthreads();

    // ========== P4: aggregate (dual-dst chains, 2-edge unroll; low-register) + score/gate dots
    int c = lane << 1;
    char* hb = (char*)h_s + ((size_t)lane << 3);
    float2 bV = *(const float2*)&bias[c];
    float2 pV = *(const float2*)&p[c];
    float2 wV = *(const float2*)&Wg[c];
    float a0[16], a1[16];
    int half = (n + 1) >> 1;
#pragma unroll
    for (int ii = 0; ii < 8; ii++) {
      int d0 = wv + (ii << 4);
      int d1 = d0 + half;
      bool h0v = (d0 < half);
      bool h1v = h0v && (d1 < n);
      int j0 = 0, e0 = 0, j1 = 0, e1 = 0;
      float dv0 = 0.f, dv1 = 0.f;
      if (h0v) { j0 = rp[d0]; e0 = rp[d0 + 1]; dv0 = dinv_s[d0]; }
      if (h1v) { j1 = rp[d1]; e1 = rp[d1 + 1]; dv1 = dinv_s[d1]; }
      float u00 = 0.f, u01 = 0.f, u10 = 0.f, u11 = 0.f;
      while (j0 + 2 <= e0 && j1 + 2 <= e1) {
        int s0 = ss[j0], s1 = ss[j0 + 1], s2 = ss[j1], s3 = ss[j1 + 1];
        float w0 = dinv_s[s0], w1 = dinv_s[s1], w2 = dinv_s[s2], w3 = dinv_s[s3];
        float2 v0 = *(const float2*)(hb + s0 * 528);
        float2 v1 = *(const float2*)(hb + s1 * 528);
        float2 v2 = *(const float2*)(hb + s2 * 528);
        float2 v3 = *(const float2*)(hb + s3 * 528);
        u00 = fmaf(w0, v0.x, u00); u01 = fmaf(w0, v0.y, u01);
        u00 = fmaf(w1, v1.x, u00); u01 = fmaf(w1, v1.y, u01);
        u10 = fmaf(w2, v2.x, u10); u11 = fmaf(w2, v2.y, u11);
        u10 = fmaf(w3, v3.x, u10); u11 = fmaf(w3, v3.y, u11);
        j0 += 2; j1 += 2;
      }
      while (j0 + 2 <= e0) {
        int s0 = ss[j0], s1 = ss[j0 + 1];
        float w0 = dinv_s[s0], w1 = dinv_s[s1];
        float2 v0 = *(const float2*)(hb + s0 * 528);
        float2 v1 = *(const float2*)(hb + s1 * 528);
        u00 = fmaf(w0, v0.x, u00); u01 = fmaf(w0, v0.y, u01);
        u00 = fmaf(w1, v1.x, u00); u01 = fmaf(w1, v1.y, u01);
        j0 += 2;
      }
      while (j0 < e0) {
        int s0 = ss[j0];
        float w0 = dinv_s[s0];
        float2 v0 = *(const float2*)(hb + s0 * 528);
        u00 = fmaf(w0, v0.x, u00); u01 = fmaf(w0, v0.y, u01);
        j0++;
      }
      while (j1 + 2 <= e1) {
        int s2 = ss[j1], s3 = ss[j1 + 1];
        float w2 = dinv_s[s2], w3 = dinv_s[s3];
        float2 v2 = *(const float2*)(hb + s2 * 528);
        float2 v3 = *(const float2*)(hb + s3 * 528);
        u10 = fmaf(w2, v2.x, u10); u11 = fmaf(w2, v2.y, u11);
        u10 = fmaf(w3, v3.x, u10); u11 = fmaf(w3, v3.y, u11);
        j1 += 2;
      }
      while (j1 < e1) {
        int s2 = ss[j1];
        float w2 = dinv_s[s2];
        float2 v2 = *(const float2*)(hb + s2 * 528);
        u10 = fmaf(w2, v2.x, u10); u11 = fmaf(w2, v2.y, u11);
        j1++;
      }
      if (h0v) {
        float2 vs = *(const float2*)(hb + d0 * 528);
        float r0 = fmaxf(fmaf(dv0, fmaf(vs.x, dv0, u00), bV.x), 0.f);
        float r1 = fmaxf(fmaf(dv0, fmaf(vs.y, dv0, u01), bV.y), 0.f);
        a0[ii] = r0; a1[ii] = r1;
        float s1 = fmaf(r0, pV.x, r1 * pV.y);
        float g1 = fmaf(r0, wV.x, r1 * wV.y);
#pragma unroll
        for (int o = 32; o > 0; o >>= 1) {
          s1 += __shfl_xor(s1, o);
          g1 += __shfl_xor(g1, o);
        }
        if (lane == 0) { rawsc_s[d0] = s1; hd[d0] = g1; }
      } else { a0[ii] = 0.f; a1[ii] = 0.f; }
      if (h1v) {
        float2 vs = *(const float2*)(hb + d1 * 528);
        float r0 = fmaxf(fmaf(dv1, fmaf(vs.x, dv1, u10), bV.x), 0.f);
        float r1 = fmaxf(fmaf(dv1, fmaf(vs.y, dv1, u11), bV.y), 0.f);
        a0[ii + 8] = r0; a1[ii + 8] = r1;
        float s1 = fmaf(r0, pV.x, r1 * pV.y);
        float g1 = fmaf(r0, wV.x, r1 * wV.y);
#pragma unroll
        for (int o = 32; o > 0; o >>= 1) {
          s1 += __shfl_xor(s1, o);
          g1 += __shfl_xor(g1, o);
        }
        if (lane == 0) { rawsc_s[d1] = s1; hd[d1] = g1; }
      } else { a0[ii + 8] = 0.f; a1[ii + 8] = 0.f; }
    }
    __syncthreads();

    // ========== P5: write aggregated h back
#pragma unroll
    for (int ii = 0; ii < 8; ii++) {
      int d0 = wv + (ii << 4);
      int d1 = d0 + half;
      if (d0 < half) *(float2*)(hb + d0 * 528) = make_float2(a0[ii], a1[ii]);
      if (d0 < half && d1 < n) *(float2*)(hb + d1 * 528) = make_float2(a0[ii + 8], a1[ii + 8]);
    }
    __syncthreads();

    // ========== P6: bitonic sort (keys = raw dot desc, idx asc)
    float key = -INFINITY;
    int id = t & 255;
    if (t < n) key = rawsc_s[t];
    for (int size = 2; size <= 256; size <<= 1) {
      for (int stride = size >> 1; stride > 0; stride >>= 1) {
        if (stride > 32) {
          if (t < 256) { sc[t] = key; idx[t] = id; }
          __syncthreads();
          float pk = 0.f; int pi = 0;
          if (t < 256) { pk = sc[t ^ stride]; pi = idx[t ^ stride]; }
          __syncthreads();
          if (t < 256) {
            bool want = ((t & size) == 0);
            bool lowr = ((t & stride) == 0);
            bool mineFirst = (key > pk) || (key == pk && id < pi);
            if (mineFirst != (want == lowr)) { key = pk; id = pi; }
          }
        } else {
          if (t < 256) {
            float pk = __shfl_xor(key, stride);
            int pi = __shfl_xor(id, stride);
            bool want = ((t & size) == 0);
            bool lowr = ((t & stride) == 0);
            bool mineFirst = (key > pk) || (key == pk && id < pi);
            if (mineFirst != (want == lowr)) { key = pk; id = pi; }
          }
        }
      }
    }
    if (t < 256) idx[t] = id;
    __syncthreads();

    // ========== P7: tn, nmap, gates + per-wave max
    float gate = -INFINITY;
    if (t < k) {
      float tnv = tanhf(key / snorm_s);
      tn[t] = tnv;
      cnt[id] = t;
      gate = fmaf(hd[id], tnv, bgv);
    }
    if (wv < 4) {
      float m = gate;
#pragma unroll
      for (int o = 32; o > 0; o >>= 1) m = fmaxf(m, __shfl_xor(m, o));
      if (lane == 0) red[wv] = m;
    }
    __syncthreads();

    // ========== P8: softmax exp+sum (waves 0-3) || edge remap in LDS (waves 8-15)
    float ex = 0.f;
    if (wv < 4) {
      float m = fmaxf(fmaxf(red[0], red[1]), fmaxf(red[2], red[3]));
      ex = (t < k) ? __expf(gate - m) : 0.f;
      float s = ex;
#pragma unroll
      for (int o = 32; o > 0; o >>= 1) s += __shfl_xor(s, o);
      if (lane == 0) red[4 + wv] = s;
    } else if (wv >= 8 && layer < 2) {
      int tt = t - 512;
#pragma unroll
      for (int q = 0; q < 4; q++) {
        int e = tt + q * 512;
        unsigned u = es[e];
        unsigned o = DEADE;
        if (u != DEADE) {
          int ns = cnt[u & 0xFFFFu], nd = cnt[u >> 16];
          if (ns >= 0 && nd >= 0) o = (unsigned)ns | ((unsigned)nd << 16);
        }
        es[e] = o;
      }
    }
    __syncthreads();

    // ========== P9: att weights + zero cnt for next layer
    if (t < 256) {
      float inv = 1.f / (red[4] + red[5] + red[6] + red[7]);
      float a = (t < k) ? ex * inv : 0.f;
      sc[t] = (layer == 2) ? a * tn[t] : a;
      cnt[t] = 0;
    }
    __syncthreads();

    if (layer < 2) {
      // ========== P10: in-LDS compaction, static 26-step unroll (205*128 <= 26*1024)
      float cv[26];
      int kk128 = k * 128;
#pragma unroll
      for (int m = 0; m < 26; m++) {
        int v = t + (m << 10);
        int r = v >> 7;
        cv[m] = (v < kk128) ? h_s[idx[r] * 132 + (v & 127)] * tn[r] : 0.f;
      }
      __syncthreads();
#pragma unroll
      for (int m = 0; m < 26; m++) {
        int v = t + (m << 10);
        if (v < kk128) h_s[(v >> 7) * 132 + (v & 127)] = cv[m];
      }
      __syncthreads();
      // ========== P11: attention partial sums over compacted rows
      if (t < 512) {
        int grp = t >> 7, c2 = t & 127;
        float pp = 0.f;
        for (int r = grp; r < k; r += 4) pp = fmaf(sc[r], h_s[r * 132 + c2], pp);
        part[t] = pp;
      }
      __syncthreads();
      if (t < 128) accout[t] += part[t] + part[128 + t] + part[256 + t] + part[384 + t];
      __syncthreads();
    } else {
      // ========== final attention (via idx, tn folded into sc) + output write
      if (t < 512) {
        int grp = t >> 7, c2 = t & 127;
        float pp = 0.f;
        for (int r = grp; r < k; r += 4) pp = fmaf(sc[r], h_s[idx[r] * 132 + c2], pp);
        part[t] = pp;
      }
      __syncthreads();
      if (t < 128)
        outp[(size_t)g * HDIM + t] =
            accout[t] + part[t] + part[128 + t] + part[256 + t] + part[384 + t];
    }
    n = k;
  }
}

// ================================================================ launch
extern "C" void kernel_launch(void* const* d_in, const int* in_sizes, int n_in,
                              void* d_out, int out_size, void* d_ws, size_t ws_size,
                              hipStream_t stream) {
  const float* x  = (const float*)d_in[0];
  const int*   ei = (const int*)d_in[1];
  const float* W0 = (const float*)d_in[2];
  const float* b0 = (const float*)d_in[3];
  const float* p0 = (const float*)d_in[4];
  const float* W1 = (const float*)d_in[5];
  const float* b1 = (const float*)d_in[6];
  const float* p1 = (const float*)d_in[7];
  const float* W2 = (const float*)d_in[8];
  const float* b2 = (const float*)d_in[9];
  const float* p2 = (const float*)d_in[10];
  const float* Wg = (const float*)d_in[11];
  const float* bg = (const float*)d_in[12];
  float* out = (float*)d_out;

  unsigned char* ws = (unsigned char*)d_ws;
  unsigned short* Wsp0 = (unsigned short*)(ws);
  unsigned short* Wsp1 = (unsigned short*)(ws + 98304ull);
  unsigned short* Wsp2 = (unsigned short*)(ws + 196608ull);

  k_wsplit<<<8, 256, 0, stream>>>(W0, Wsp0);
  k_wsplit<<<8, 256, 0, stream>>>(W1, Wsp1);
  k_wsplit<<<8, 256, 0, stream>>>(W2, Wsp2);
  k_net<<<GCOUNT, 1024, 0, stream>>>(x, ei, Wsp0, Wsp1, Wsp2,
                                     b0, p0, b1, p1, b2, p2, Wg, bg, out);
}

// Round 10
// 417.081 us; speedup vs baseline: 1.4532x; 1.0006x over previous
//
#include <hip/hip_runtime.h>
#include <math.h>

#define GCOUNT 512
#define HDIM 128
#define EPG 2048                 // edge slots per graph (fixed across layers)
#define E_TOTAL (GCOUNT * EPG)   // 1,048,576
#define DEADE 0xFFFFFFFFu

typedef __attribute__((ext_vector_type(8))) short short8;
typedef __attribute__((ext_vector_type(4))) float f32x4;

__device__ inline unsigned short f2bf(float f) {
  unsigned int u = __float_as_uint(f);
  return (unsigned short)((u + 0x7FFFu + ((u >> 16) & 1u)) >> 16);
}
__device__ inline float bf2f(unsigned short s) {
  return __uint_as_float(((unsigned int)s) << 16);
}

// ---------------------------------------------------------------- W prepack: bf16 3-split, MFMA-B-fragment layout
__global__ __launch_bounds__(256) void k_wsplit(const float* __restrict__ W,
                                                unsigned short* __restrict__ out) {
  int t = blockIdx.x * 256 + threadIdx.x;   // 2048 = (kc*8+ct)*64+lane
  int lane = t & 63;
  int ct = (t >> 6) & 7;
  int kc = t >> 9;
  int kbase = kc * 32 + (lane >> 4) * 8;
  int col = ct * 16 + (lane & 15);
#pragma unroll
  for (int j = 0; j < 8; j++) {
    float w = W[(size_t)(kbase + j) * HDIM + col];
    unsigned short h0 = f2bf(w);  float g0 = bf2f(h0);
    float r1 = w - g0;
    unsigned short h1 = f2bf(r1); float g1 = bf2f(h1);
    unsigned short h2 = f2bf(r1 - g1);
    int base = (kc * 8 + ct) * 512 + lane * 8 + j;
    out[base]         = h0;
    out[base + 16384] = h1;
    out[base + 32768] = h2;
  }
}

// ---------------------------------------------------------------- whole network, one block per graph
__global__ __launch_bounds__(1024, 1) void k_net(
    const float* __restrict__ xIn, const int* __restrict__ ei0,
    const unsigned short* __restrict__ Ws0,
    const unsigned short* __restrict__ Ws1,
    const unsigned short* __restrict__ Ws2,
    const float* __restrict__ b0, const float* __restrict__ p0,
    const float* __restrict__ b1, const float* __restrict__ p1,
    const float* __restrict__ b2, const float* __restrict__ p2,
    const float* __restrict__ Wg, const float* __restrict__ bgp,
    float* __restrict__ outp) {

  __shared__ __align__(16) float h_s[256 * 132];   // 135168 B
  __shared__ unsigned int es[EPG];                 // 8 KB  (src | dst<<16), DEADE = dead
  __shared__ unsigned short ss[EPG];               // 4 KB  CSR-sorted local src ids
  __shared__ int cnt[256];                         // degree -> nmap
  __shared__ int ofs[256];
  __shared__ int rp[260];
  __shared__ float dinv_s[256];
  __shared__ float rawsc_s[256];
  __shared__ float hd[256];                        // h' . Wg per row
  __shared__ float sc[256];                        // sort exchange -> att weights
  __shared__ int   idx[256];
  __shared__ float tn[256];
  __shared__ float accout[128];
  __shared__ float part[512];
  __shared__ float red[8];
  __shared__ float snorm_s;

  int g = blockIdx.x, t = threadIdx.x;
  int lane = t & 63, wv = t >> 6;
  int eb = g * EPG;
  float bgv = bgp[0];

  // ========== P0: stage x + edge loads to regs (waves 8-15) + zero cnt/accout
  {
    const float4* xg = (const float4*)(xIn + (size_t)g * 256 * HDIM);
    for (int i = t; i < 8192; i += 1024) {
      int r = i >> 5, q = i & 31;
      *(float4*)&h_s[r * 132 + (q << 2)] = xg[i];
    }
  }
  int esl[4], edl[4];
  if (wv >= 8) {
    int tt = t - 512;
#pragma unroll
    for (int q = 0; q < 4; q++) {
      int e = tt + q * 512;
      esl[q] = ei0[eb + e] - g * 256;
      edl[q] = ei0[E_TOTAL + eb + e] - g * 256;
    }
  }
  if (t < 256) cnt[t] = 0;
  if (t < 128) accout[t] = 0.f;
  __syncthreads();

  int n = 256;
#pragma unroll 1
  for (int layer = 0; layer < 3; layer++) {
    const unsigned short* Ws = (layer == 0) ? Ws0 : (layer == 1 ? Ws1 : Ws2);
    const float* bias = (layer == 0) ? b0 : (layer == 1 ? b1 : b2);
    const float* p    = (layer == 0) ? p0 : (layer == 1 ? p1 : p2);
    int k = (layer == 0) ? 205 : (layer == 1 ? 164 : 132);
    int T2 = (n + 31) >> 5;

    // ========== P1: GEMM (waves < T2) || histogram (+es write, L0) (waves >= 8)
    if (wv < T2) {
      int rbase = wv * 32;
      int arow = lane & 15, kgrp = (lane >> 4) * 8;
      f32x4 acc[2][8];
#pragma unroll
      for (int rt = 0; rt < 2; rt++)
#pragma unroll
        for (int ct = 0; ct < 8; ct++) acc[rt][ct] = (f32x4){0.f, 0.f, 0.f, 0.f};
#pragma unroll
      for (int kc = 0; kc < 4; kc++) {
        short8 fa0[2], fa1[2], fa2[2];
#pragma unroll
        for (int rt = 0; rt < 2; rt++) {
          const float* ap = &h_s[(rbase + rt * 16 + arow) * 132 + kc * 32 + kgrp];
          float4 x0 = *(const float4*)ap;
          float4 x1 = *(const float4*)(ap + 4);
          float v[8] = {x0.x, x0.y, x0.z, x0.w, x1.x, x1.y, x1.z, x1.w};
#pragma unroll
          for (int j = 0; j < 8; j++) {
            float a = v[j];
            unsigned short q0 = f2bf(a);  float g0 = bf2f(q0);
            float r1 = a - g0;
            unsigned short q1 = f2bf(r1); float g1 = bf2f(q1);
            unsigned short q2 = f2bf(r1 - g1);
            fa0[rt][j] = (short)q0; fa1[rt][j] = (short)q1; fa2[rt][j] = (short)q2;
          }
        }
#pragma unroll
        for (int ct = 0; ct < 8; ct++) {
          const unsigned short* wb = Ws + (kc * 8 + ct) * 512 + lane * 8;
          short8 w0 = *(const short8*)wb;
          short8 w1 = *(const short8*)(wb + 16384);
          short8 w2 = *(const short8*)(wb + 32768);
#pragma unroll
          for (int rt = 0; rt < 2; rt++) {
            acc[rt][ct] = __builtin_amdgcn_mfma_f32_16x16x32_bf16(fa0[rt], w0, acc[rt][ct], 0, 0, 0);
            acc[rt][ct] = __builtin_amdgcn_mfma_f32_16x16x32_bf16(fa0[rt], w1, acc[rt][ct], 0, 0, 0);
            acc[rt][ct] = __builtin_amdgcn_mfma_f32_16x16x32_bf16(fa1[rt], w0, acc[rt][ct], 0, 0, 0);
            acc[rt][ct] = __builtin_amdgcn_mfma_f32_16x16x32_bf16(fa1[rt], w1, acc[rt][ct], 0, 0, 0);
            acc[rt][ct] = __builtin_amdgcn_mfma_f32_16x16x32_bf16(fa0[rt], w2, acc[rt][ct], 0, 0, 0);
            acc[rt][ct] = __builtin_amdgcn_mfma_f32_16x16x32_bf16(fa2[rt], w0, acc[rt][ct], 0, 0, 0);
          }
        }
      }
      int crow = (lane >> 4) * 4, ccol = lane & 15;
#pragma unroll
      for (int rt = 0; rt < 2; rt++)
#pragma unroll
        for (int ct = 0; ct < 8; ct++)
#pragma unroll
          for (int reg = 0; reg < 4; reg++)
            h_s[(rbase + rt * 16 + crow + reg) * 132 + ct * 16 + ccol] = acc[rt][ct][reg];
    } else if (wv >= 8) {
      int tt = t - 512;
      if (layer == 0) {
#pragma unroll
        for (int q = 0; q < 4; q++) {
          atomicAdd(&cnt[edl[q]], 1);
          es[tt + q * 512] = (unsigned)esl[q] | ((unsigned)edl[q] << 16);
        }
      } else {
#pragma unroll
        for (int q = 0; q < 4; q++) {
          unsigned u = es[tt + q * 512];
          if (u != DEADE) atomicAdd(&cnt[u >> 16], 1);
        }
      }
    }
    __syncthreads();

    // ========== P2: dinv (t<256) + scan (wave0) + snorm (wave1)
    if (t < 256) dinv_s[t] = rsqrtf((float)cnt[t] + 1.0f);
    if (wv == 0) {
      int4 c4 = *(const int4*)&cnt[lane << 2];
      int s4 = c4.x + c4.y + c4.z + c4.w;
      int run = s4;
#pragma unroll
      for (int o = 1; o < 64; o <<= 1) {
        int v = __shfl_up(run, o);
        if (lane >= o) run += v;
      }
      int base = run - s4;
      int v1 = base + c4.x, v2 = v1 + c4.y, v3 = v2 + c4.z;
      int li = lane << 2;
      rp[li] = base; rp[li + 1] = v1; rp[li + 2] = v2; rp[li + 3] = v3;
      ofs[li] = base; ofs[li + 1] = v1; ofs[li + 2] = v2; ofs[li + 3] = v3;
      if (lane == 63) rp[256] = run;
    }
    if (wv == 1) {
      float q = p[lane] * p[lane] + p[lane + 64] * p[lane + 64];
#pragma unroll
      for (int o = 32; o > 0; o >>= 1) q += __shfl_xor(q, o);
      if (lane == 0) snorm_s = sqrtf(q);
    }
    __syncthreads();

    // ========== P3: scatter CSR (all threads) + preset nmap
    if (t < 256) cnt[t] = -1;
    for (int e = t; e < EPG; e += 1024) {
      unsigned u = es[e];
      if (u != DEADE) {
        int pos = atomicAdd(&ofs[u >> 16], 1);
        ss[pos] = (unsigned short)(u & 0xFFFFu);
      }
    }
    __syncthreads();

    // ========== P4: aggregate (dual-dst chains, 2-edge unroll) + score/gate dots
    int c = lane << 1;
    char* hb = (char*)h_s + ((size_t)lane << 3);
    float2 bV = *(const float2*)&bias[c];
    float2 pV = *(const float2*)&p[c];
    float2 wV = *(const float2*)&Wg[c];
    float a0[16], a1[16];
    int half = (n + 1) >> 1;
#pragma unroll
    for (int ii = 0; ii < 8; ii++) {
      int d0 = wv + (ii << 4);
      int d1 = d0 + half;
      bool h0v = (d0 < half);
      bool h1v = h0v && (d1 < n);
      int j0 = 0, e0 = 0, j1 = 0, e1 = 0;
      float dv0 = 0.f, dv1 = 0.f;
      if (h0v) { j0 = rp[d0]; e0 = rp[d0 + 1]; dv0 = dinv_s[d0]; }
      if (h1v) { j1 = rp[d1]; e1 = rp[d1 + 1]; dv1 = dinv_s[d1]; }
      float u00 = 0.f, u01 = 0.f, u10 = 0.f, u11 = 0.f;
      while (j0 + 2 <= e0 && j1 + 2 <= e1) {
        int s0 = ss[j0], s1 = ss[j0 + 1], s2 = ss[j1], s3 = ss[j1 + 1];
        float w0 = dinv_s[s0], w1 = dinv_s[s1], w2 = dinv_s[s2], w3 = dinv_s[s3];
        float2 v0 = *(const float2*)(hb + s0 * 528);
        float2 v1 = *(const float2*)(hb + s1 * 528);
        float2 v2 = *(const float2*)(hb + s2 * 528);
        float2 v3 = *(const float2*)(hb + s3 * 528);
        u00 = fmaf(w0, v0.x, u00); u01 = fmaf(w0, v0.y, u01);
        u00 = fmaf(w1, v1.x, u00); u01 = fmaf(w1, v1.y, u01);
        u10 = fmaf(w2, v2.x, u10); u11 = fmaf(w2, v2.y, u11);
        u10 = fmaf(w3, v3.x, u10); u11 = fmaf(w3, v3.y, u11);
        j0 += 2; j1 += 2;
      }
      while (j0 + 2 <= e0) {
        int s0 = ss[j0], s1 = ss[j0 + 1];
        float w0 = dinv_s[s0], w1 = dinv_s[s1];
        float2 v0 = *(const float2*)(hb + s0 * 528);
        float2 v1 = *(const float2*)(hb + s1 * 528);
        u00 = fmaf(w0, v0.x, u00); u01 = fmaf(w0, v0.y, u01);
        u00 = fmaf(w1, v1.x, u00); u01 = fmaf(w1, v1.y, u01);
        j0 += 2;
      }
      while (j0 < e0) {
        int s0 = ss[j0];
        float w0 = dinv_s[s0];
        float2 v0 = *(const float2*)(hb + s0 * 528);
        u00 = fmaf(w0, v0.x, u00); u01 = fmaf(w0, v0.y, u01);
        j0++;
      }
      while (j1 + 2 <= e1) {
        int s2 = ss[j1], s3 = ss[j1 + 1];
        float w2 = dinv_s[s2], w3 = dinv_s[s3];
        float2 v2 = *(const float2*)(hb + s2 * 528);
        float2 v3 = *(const float2*)(hb + s3 * 528);
        u10 = fmaf(w2, v2.x, u10); u11 = fmaf(w2, v2.y, u11);
        u10 = fmaf(w3, v3.x, u10); u11 = fmaf(w3, v3.y, u11);
        j1 += 2;
      }
      while (j1 < e1) {
        int s2 = ss[j1];
        float w2 = dinv_s[s2];
        float2 v2 = *(const float2*)(hb + s2 * 528);
        u10 = fmaf(w2, v2.x, u10); u11 = fmaf(w2, v2.y, u11);
        j1++;
      }
      if (h0v) {
        float2 vs = *(const float2*)(hb + d0 * 528);
        float r0 = fmaxf(fmaf(dv0, fmaf(vs.x, dv0, u00), bV.x), 0.f);
        float r1 = fmaxf(fmaf(dv0, fmaf(vs.y, dv0, u01), bV.y), 0.f);
        a0[ii] = r0; a1[ii] = r1;
        float s1 = fmaf(r0, pV.x, r1 * pV.y);
        float g1 = fmaf(r0, wV.x, r1 * wV.y);
#pragma unroll
        for (int o = 32; o > 0; o >>= 1) {
          s1 += __shfl_xor(s1, o);
          g1 += __shfl_xor(g1, o);
        }
        if (lane == 0) { rawsc_s[d0] = s1; hd[d0] = g1; }
      } else { a0[ii] = 0.f; a1[ii] = 0.f; }
      if (h1v) {
        float2 vs = *(const float2*)(hb + d1 * 528);
        float r0 = fmaxf(fmaf(dv1, fmaf(vs.x, dv1, u10), bV.x), 0.f);
        float r1 = fmaxf(fmaf(dv1, fmaf(vs.y, dv1, u11), bV.y), 0.f);
        a0[ii + 8] = r0; a1[ii + 8] = r1;
        float s1 = fmaf(r0, pV.x, r1 * pV.y);
        float g1 = fmaf(r0, wV.x, r1 * wV.y);
#pragma unroll
        for (int o = 32; o > 0; o >>= 1) {
          s1 += __shfl_xor(s1, o);
          g1 += __shfl_xor(g1, o);
        }
        if (lane == 0) { rawsc_s[d1] = s1; hd[d1] = g1; }
      } else { a0[ii + 8] = 0.f; a1[ii + 8] = 0.f; }
    }
    __syncthreads();

    // ========== P5: write aggregated h back
#pragma unroll
    for (int ii = 0; ii < 8; ii++) {
      int d0 = wv + (ii << 4);
      int d1 = d0 + half;
      if (d0 < half) *(float2*)(hb + d0 * 528) = make_float2(a0[ii], a1[ii]);
      if (d0 < half && d1 < n) *(float2*)(hb + d1 * 528) = make_float2(a0[ii + 8], a1[ii + 8]);
    }
    __syncthreads();

    // ========== P6: bitonic sort (keys = raw dot desc, idx asc)
    float key = -INFINITY;
    int id = t & 255;
    if (t < n) key = rawsc_s[t];
    for (int size = 2; size <= 256; size <<= 1) {
      for (int stride = size >> 1; stride > 0; stride >>= 1) {
        if (stride > 32) {
          if (t < 256) { sc[t] = key; idx[t] = id; }
          __syncthreads();
          float pk = 0.f; int pi = 0;
          if (t < 256) { pk = sc[t ^ stride]; pi = idx[t ^ stride]; }
          __syncthreads();
          if (t < 256) {
            bool want = ((t & size) == 0);
            bool lowr = ((t & stride) == 0);
            bool mineFirst = (key > pk) || (key == pk && id < pi);
            if (mineFirst != (want == lowr)) { key = pk; id = pi; }
          }
        } else {
          if (t < 256) {
            float pk = __shfl_xor(key, stride);
            int pi = __shfl_xor(id, stride);
            bool want = ((t & size) == 0);
            bool lowr = ((t & stride) == 0);
            bool mineFirst = (key > pk) || (key == pk && id < pi);
            if (mineFirst != (want == lowr)) { key = pk; id = pi; }
          }
        }
      }
    }
    if (t < 256) idx[t] = id;
    __syncthreads();

    // ========== P7: tn, nmap, gates + per-wave max
    float gate = -INFINITY;
    if (t < k) {
      float tnv = tanhf(key / snorm_s);
      tn[t] = tnv;
      cnt[id] = t;
      gate = fmaf(hd[id], tnv, bgv);
    }
    if (wv < 4) {
      float m = gate;
#pragma unroll
      for (int o = 32; o > 0; o >>= 1) m = fmaxf(m, __shfl_xor(m, o));
      if (lane == 0) red[wv] = m;
    }
    __syncthreads();

    // ========== P8: softmax exp+sum (waves 0-3) || edge remap in LDS (waves 8-15)
    float ex = 0.f;
    if (wv < 4) {
      float m = fmaxf(fmaxf(red[0], red[1]), fmaxf(red[2], red[3]));
      ex = (t < k) ? __expf(gate - m) : 0.f;
      float s = ex;
#pragma unroll
      for (int o = 32; o > 0; o >>= 1) s += __shfl_xor(s, o);
      if (lane == 0) red[4 + wv] = s;
    } else if (wv >= 8 && layer < 2) {
      int tt = t - 512;
#pragma unroll
      for (int q = 0; q < 4; q++) {
        int e = tt + q * 512;
        unsigned u = es[e];
        unsigned o = DEADE;
        if (u != DEADE) {
          int ns = cnt[u & 0xFFFFu], nd = cnt[u >> 16];
          if (ns >= 0 && nd >= 0) o = (unsigned)ns | ((unsigned)nd << 16);
        }
        es[e] = o;
      }
    }
    __syncthreads();

    // ========== P9: att weights + zero cnt for next layer
    if (t < 256) {
      float inv = 1.f / (red[4] + red[5] + red[6] + red[7]);
      float a = (t < k) ? ex * inv : 0.f;
      sc[t] = (layer == 2) ? a * tn[t] : a;
      cnt[t] = 0;
    }
    __syncthreads();

    if (layer < 2) {
      // ========== P10: in-LDS compaction, static 26-step unroll (205*128 <= 26*1024)
      float cv[26];
      int kk128 = k * 128;
#pragma unroll
      for (int m = 0; m < 26; m++) {
        int v = t + (m << 10);
        int r = v >> 7;
        cv[m] = (v < kk128) ? h_s[idx[r] * 132 + (v & 127)] * tn[r] : 0.f;
      }
      __syncthreads();
#pragma unroll
      for (int m = 0; m < 26; m++) {
        int v = t + (m << 10);
        if (v < kk128) h_s[(v >> 7) * 132 + (v & 127)] = cv[m];
      }
      __syncthreads();
      // ========== P11: attention partial sums over compacted rows
      if (t < 512) {
        int grp = t >> 7, c2 = t & 127;
        float pp = 0.f;
        for (int r = grp; r < k; r += 4) pp = fmaf(sc[r], h_s[r * 132 + c2], pp);
        part[t] = pp;
      }
      __syncthreads();
      if (t < 128) accout[t] += part[t] + part[128 + t] + part[256 + t] + part[384 + t];
      __syncthreads();
    } else {
      // ========== final attention (via idx, tn folded into sc) + output write
      if (t < 512) {
        int grp = t >> 7, c2 = t & 127;
        float pp = 0.f;
        for (int r = grp; r < k; r += 4) pp = fmaf(sc[r], h_s[idx[r] * 132 + c2], pp);
        part[t] = pp;
      }
      __syncthreads();
      if (t < 128)
        outp[(size_t)g * HDIM + t] =
            accout[t] + part[t] + part[128 + t] + part[256 + t] + part[384 + t];
    }
    n = k;
  }
}

// ================================================================ launch
extern "C" void kernel_launch(void* const* d_in, const int* in_sizes, int n_in,
                              void* d_out, int out_size, void* d_ws, size_t ws_size,
                              hipStream_t stream) {
  const float* x  = (const float*)d_in[0];
  const int*   ei = (const int*)d_in[1];
  const float* W0 = (const float*)d_in[2];
  const float* b0 = (const float*)d_in[3];
  const float* p0 = (const float*)d_in[4];
  const float* W1 = (const float*)d_in[5];
  const float* b1 = (const float*)d_in[6];
  const float* p1 = (const float*)d_in[7];
  const float* W2 = (const float*)d_in[8];
  const float* b2 = (const float*)d_in[9];
  const float* p2 = (const float*)d_in[10];
  const float* Wg = (const float*)d_in[11];
  const float* bg = (const float*)d_in[12];
  float* out = (float*)d_out;

  unsigned char* ws = (unsigned char*)d_ws;
  unsigned short* Wsp0 = (unsigned short*)(ws);
  unsigned short* Wsp1 = (unsigned short*)(ws + 98304ull);
  unsigned short* Wsp2 = (unsigned short*)(ws + 196608ull);

  k_wsplit<<<8, 256, 0, stream>>>(W0, Wsp0);
  k_wsplit<<<8, 256, 0, stream>>>(W1, Wsp1);
  k_wsplit<<<8, 256, 0, stream>>>(W2, Wsp2);
  k_net<<<GCOUNT, 1024, 0, stream>>>(x, ei, Wsp0, Wsp1, Wsp2,
                                     b0, p0, b1, p1, b2, p2, Wg, bg, out);
}